// Round 1
// baseline (382.248 us; speedup 1.0000x reference)
//
#include <hip/hip_runtime.h>

// ContrastiveWeight: T=128 views, N=2048 samples, D=128 dims.
// out = [avg_loss (1), sim (N*T*T), logits (N*T*127)] all fp32.

#define TT 128
#define NB 2048
#define DD 128
#define LSTRIDE 136   // LDS row stride in bf16 elements: 136*2=272 B, 16B-aligned, +8 pad kills bank conflicts

typedef __attribute__((ext_vector_type(8))) short short8;
typedef __attribute__((ext_vector_type(4))) float f32x4;

__device__ __forceinline__ unsigned short f2bf(float f) {
  union { float f; unsigned u; } v; v.f = f;
  unsigned u = v.u + 0x7FFFu + ((v.u >> 16) & 1u);  // RNE
  return (unsigned short)(u >> 16);
}
__device__ __forceinline__ float bf2f(unsigned short s) {
  union { unsigned u; float f; } v; v.u = ((unsigned)s) << 16;
  return v.f;
}

__global__ __launch_bounds__(256, 4) void contrastive_kernel(
    const float* __restrict__ emb, float* __restrict__ out) {
  // Single LDS buffer, reused: phase A/B holds normalized X (bf16),
  // after barrier holds sim G (bf16). 128*136*2 = 34816 B.
  __shared__ unsigned short SM[TT * LSTRIDE];
  __shared__ float red[4];

  const int n = blockIdx.x;
  const int tid = threadIdx.x;

  // ---------------- Phase A: load, normalize, bf16 -> LDS ----------------
  {
    const int lane = tid & 31;          // 32 lanes per row (128 floats = 32 x float4)
    const int rbase = tid >> 5;         // 0..7
    for (int it = 0; it < 16; ++it) {
      const int r = it * 8 + rbase;
      const float4 v = *(const float4*)(emb + ((size_t)r * NB + n) * DD + lane * 4);
      float ss = v.x * v.x + v.y * v.y + v.z * v.z + v.w * v.w;
      #pragma unroll
      for (int off = 16; off > 0; off >>= 1) ss += __shfl_xor(ss, off, 32);
      const float scale = 1.0f / fmaxf(sqrtf(ss), 1e-12f);
      const unsigned lo = (unsigned)f2bf(v.x * scale) | ((unsigned)f2bf(v.y * scale) << 16);
      const unsigned hi = (unsigned)f2bf(v.z * scale) | ((unsigned)f2bf(v.w * scale) << 16);
      *(uint2*)&SM[r * LSTRIDE + lane * 4] = make_uint2(lo, hi);
    }
  }
  __syncthreads();

  // ---------------- Phase B: G = Xn * Xn^T via bf16 MFMA ----------------
  // 8x8 grid of 16x16 tiles; wave w owns tile-rows {2w, 2w+1} x all 8 cols.
  {
    const int l = tid & 63;
    const int w = tid >> 6;
    const int m = l & 15;       // row-within-tile for A/B frags
    const int quad = l >> 4;    // k-chunk selector within MFMA
    f32x4 acc[2][8];
    #pragma unroll
    for (int i = 0; i < 2; ++i)
      #pragma unroll
      for (int j = 0; j < 8; ++j) acc[i][j] = (f32x4){0.f, 0.f, 0.f, 0.f};

    const int ti0 = w * 2;
    #pragma unroll
    for (int kk = 0; kk < 4; ++kk) {
      const int koff = kk * 32 + quad * 8;
      // A frag: lane holds A[m][koff..koff+8) ; B frag identical pattern (B = X^T)
      const short8 a0 = *(const short8*)&SM[(ti0 * 16 + m) * LSTRIDE + koff];
      const short8 a1 = *(const short8*)&SM[((ti0 + 1) * 16 + m) * LSTRIDE + koff];
      #pragma unroll
      for (int tj = 0; tj < 8; ++tj) {
        const short8 b = *(const short8*)&SM[(tj * 16 + m) * LSTRIDE + koff];
        acc[0][tj] = __builtin_amdgcn_mfma_f32_16x16x32_bf16(a0, b, acc[0][tj], 0, 0, 0);
        acc[1][tj] = __builtin_amdgcn_mfma_f32_16x16x32_bf16(a1, b, acc[1][tj], 0, 0, 0);
      }
    }
    __syncthreads();  // everyone done reading X from SM; safe to overwrite with G

    // Epilogue: C/D layout col=lane&15, row=quad*4+reg (symmetric G => swap-safe)
    #pragma unroll
    for (int i = 0; i < 2; ++i) {
      const int rowbase = (ti0 + i) * 16 + quad * 4;
      #pragma unroll
      for (int tj = 0; tj < 8; ++tj) {
        #pragma unroll
        for (int r = 0; r < 4; ++r) {
          SM[(rowbase + r) * LSTRIDE + tj * 16 + m] = f2bf(acc[i][tj][r]);
        }
      }
    }
  }
  __syncthreads();

  // ---------------- Phase C1: sim -> global (coalesced) ----------------
  float* d_sim = out + 1 + (size_t)n * (TT * TT);
  #pragma unroll 4
  for (int i = 0; i < 64; ++i) {
    const int idx = i * 256 + tid;
    const int row = idx >> 7, col = idx & 127;
    d_sim[idx] = bf2f(SM[row * LSTRIDE + col]);
  }

  // ---------------- Phase C2: logits gather -> global (coalesced) ----------------
  // Row t: positives = { tm+32q : q != tq } ascending (tm=t&31, tq=t>>5);
  // negatives = ascending j excluding {tm, tm+32, tm+64, tm+96}.
  float* d_log = out + 1 + (size_t)NB * (TT * TT) + (size_t)n * (TT * 127);
  for (int i = 0; i < 64; ++i) {
    const int idx = i * 256 + tid;
    if (idx >= TT * 127) break;
    const int t = idx / 127;
    const int k = idx - t * 127;
    const int tm = t & 31, tq = t >> 5;
    int j;
    if (k < 3) {
      const int q = k + (k >= tq ? 1 : 0);
      j = tm + 32 * q;
    } else {
      j = k - 3;
      #pragma unroll
      for (int q = 0; q < 4; ++q)
        if (tm + 32 * q <= j) j++;
    }
    d_log[idx] = bf2f(SM[t * LSTRIDE + j]);
  }

  // ---------------- Phase C3: loss ----------------
  // rowloss = 3*lse(5*sim[t, j!=t]) - sum_{pos} 5*sim[t,p];  |z|<=5 so no max-pass.
  {
    const int t = tid >> 1;
    const int h = tid & 1;
    float s = 0.f, psum = 0.f;
    const int c0 = h * 64;
    for (int j = c0; j < c0 + 64; ++j) {
      if (j == t) continue;
      const float z = 5.0f * bf2f(SM[t * LSTRIDE + j]);
      s += __expf(z);
      if (((j ^ t) & 31) == 0) psum += z;  // positive iff j==t (mod 32), j!=t
    }
    s += __shfl_xor(s, 1, 64);
    psum += __shfl_xor(psum, 1, 64);
    float rowloss = (h == 0) ? (3.0f * __logf(s) - psum) : 0.f;
    #pragma unroll
    for (int off = 32; off >= 1; off >>= 1) rowloss += __shfl_xor(rowloss, off, 64);
    if ((tid & 63) == 0) red[tid >> 6] = rowloss;
    __syncthreads();
    if (tid == 0) {
      const float blocksum = red[0] + red[1] + red[2] + red[3];
      atomicAdd(out, blocksum * (1.0f / ((float)TT * (float)NB)));
    }
  }
}

extern "C" void kernel_launch(void* const* d_in, const int* in_sizes, int n_in,
                              void* d_out, int out_size, void* d_ws, size_t ws_size,
                              hipStream_t stream) {
  const float* emb = (const float*)d_in[0];
  float* out = (float*)d_out;
  // out[0] is accumulated via atomicAdd; zero it first (graph-capture-safe).
  hipMemsetAsync(d_out, 0, sizeof(float), stream);
  contrastive_kernel<<<dim3(NB), dim3(256), 0, stream>>>(emb, out);
}

// Round 2
// 381.042 us; speedup vs baseline: 1.0032x; 1.0032x over previous
//
#include <hip/hip_runtime.h>

// ContrastiveWeight: T=128 views, N=2048 samples, D=128 dims.
// out = [avg_loss (1), sim (N*T*T), logits (N*T*127)] all fp32.

#define TT 128
#define NB 2048
#define DD 128
#define XSTRIDE 136   // bf16 elems; 272 B row, 16B-aligned for ds_read_b128; phase-B conflicts 2-way (free)
#define GSTRIDE 130   // bf16 elems; 260 B row; 65 dwords == 1 (mod 32) -> conflict-free row-parallel reads

typedef __attribute__((ext_vector_type(8))) short short8;
typedef __attribute__((ext_vector_type(4))) float f32x4;

__device__ __forceinline__ unsigned short f2bf(float f) {
  union { float f; unsigned u; } v; v.f = f;
  unsigned u = v.u + 0x7FFFu + ((v.u >> 16) & 1u);  // RNE
  return (unsigned short)(u >> 16);
}
__device__ __forceinline__ float bf2f(unsigned short s) {
  union { unsigned u; float f; } v; v.u = ((unsigned)s) << 16;
  return v.f;
}

__global__ __launch_bounds__(256, 4) void contrastive_kernel(
    const float* __restrict__ emb, float* __restrict__ out) {
  // One LDS buffer, two lifetimes: X (bf16, stride 136) then G (bf16, stride 130).
  __shared__ unsigned short SM[TT * XSTRIDE];
  __shared__ float red[4];

  const int n = blockIdx.x;
  const int tid = threadIdx.x;

  // ---------------- Phase A: load, normalize, bf16 -> LDS ----------------
  // Two-stage prefetch: 8 independent float4 loads in flight per wave per batch
  // (64 KB in flight per CU at 16 waves -> read latency fully hidden).
  {
    const int lane = tid & 31;          // 32 lanes x float4 = 512 B per row
    const int rbase = tid >> 5;         // 0..7
    const float* base = emb + (size_t)n * DD + (size_t)lane * 4;
    #pragma unroll
    for (int b = 0; b < 2; ++b) {
      float4 v[8];
      #pragma unroll
      for (int u = 0; u < 8; ++u) {
        const int r = (b * 8 + u) * 8 + rbase;
        v[u] = *(const float4*)(base + (size_t)r * (NB * DD));
      }
      #pragma unroll
      for (int u = 0; u < 8; ++u) {
        const int r = (b * 8 + u) * 8 + rbase;
        float ss = v[u].x * v[u].x + v[u].y * v[u].y + v[u].z * v[u].z + v[u].w * v[u].w;
        #pragma unroll
        for (int off = 16; off > 0; off >>= 1) ss += __shfl_xor(ss, off, 32);
        const float scale = rsqrtf(fmaxf(ss, 1e-24f));   // norm ~ sqrt(128), never tiny
        const unsigned lo = (unsigned)f2bf(v[u].x * scale) | ((unsigned)f2bf(v[u].y * scale) << 16);
        const unsigned hi = (unsigned)f2bf(v[u].z * scale) | ((unsigned)f2bf(v[u].w * scale) << 16);
        *(uint2*)&SM[r * XSTRIDE + lane * 4] = make_uint2(lo, hi);
      }
    }
  }
  __syncthreads();

  // ---------------- Phase B: G = Xn * Xn^T via bf16 MFMA ----------------
  // 8x8 grid of 16x16 tiles; wave w owns tile-rows {2w, 2w+1} x all 8 cols.
  {
    const int l = tid & 63;
    const int w = tid >> 6;
    const int m = l & 15;       // row-within-tile for A/B frags
    const int quad = l >> 4;    // k-chunk selector
    f32x4 acc[2][8];
    #pragma unroll
    for (int i = 0; i < 2; ++i)
      #pragma unroll
      for (int j = 0; j < 8; ++j) acc[i][j] = (f32x4){0.f, 0.f, 0.f, 0.f};

    const int ti0 = w * 2;
    #pragma unroll
    for (int kk = 0; kk < 4; ++kk) {
      const int koff = kk * 32 + quad * 8;
      const short8 a0 = *(const short8*)&SM[(ti0 * 16 + m) * XSTRIDE + koff];
      const short8 a1 = *(const short8*)&SM[((ti0 + 1) * 16 + m) * XSTRIDE + koff];
      #pragma unroll
      for (int tj = 0; tj < 8; ++tj) {
        const short8 b = *(const short8*)&SM[(tj * 16 + m) * XSTRIDE + koff];
        acc[0][tj] = __builtin_amdgcn_mfma_f32_16x16x32_bf16(a0, b, acc[0][tj], 0, 0, 0);
        acc[1][tj] = __builtin_amdgcn_mfma_f32_16x16x32_bf16(a1, b, acc[1][tj], 0, 0, 0);
      }
    }
    __syncthreads();  // all waves done reading X; safe to overwrite SM with G

    // Epilogue: C/D layout col=lane&15, row=quad*4+reg (G symmetric => swap-safe).
    // Write with GSTRIDE for conflict-free phase C.
    #pragma unroll
    for (int i = 0; i < 2; ++i) {
      const int rowbase = (ti0 + i) * 16 + quad * 4;
      #pragma unroll
      for (int tj = 0; tj < 8; ++tj) {
        #pragma unroll
        for (int r = 0; r < 4; ++r) {
          SM[(rowbase + r) * GSTRIDE + tj * 16 + m] = f2bf(acc[i][tj][r]);
        }
      }
    }
  }
  __syncthreads();

  // ---------------- Phase C1: sim -> global (coalesced, u32 LDS reads) ----------------
  float* d_sim = out + 1 + (size_t)n * (TT * TT);
  #pragma unroll 4
  for (int i = 0; i < 32; ++i) {
    const int idx2 = i * 512 + tid * 2;           // pair of consecutive elements
    const int row = idx2 >> 7, col = idx2 & 127;  // col even
    const unsigned pair = *(const unsigned*)&SM[row * GSTRIDE + col];
    d_sim[idx2]     = bf2f((unsigned short)(pair & 0xFFFF));
    d_sim[idx2 + 1] = bf2f((unsigned short)(pair >> 16));
  }

  // ---------------- Phase C2: logits gather -> global (coalesced) ----------------
  // Row t (tm=t&31, tq=t>>5): positives = {tm+32q : q != tq} ascending;
  // negatives = ascending j excluding {tm, tm+32, tm+64, tm+96}.
  float* d_log = out + 1 + (size_t)NB * (TT * TT) + (size_t)n * (TT * 127);
  for (int i = 0; i < 64; ++i) {
    const int idx = i * 256 + tid;
    if (idx >= TT * 127) break;
    const int t = idx / 127;
    const int k = idx - t * 127;
    const int tm = t & 31, tq = t >> 5;
    int j;
    if (k < 3) {
      const int q = k + (k >= tq ? 1 : 0);
      j = tm + 32 * q;
    } else {
      j = k - 3;
      #pragma unroll
      for (int q = 0; q < 4; ++q)
        if (tm + 32 * q <= j) j++;
    }
    d_log[idx] = bf2f(SM[t * GSTRIDE + j]);
  }

  // ---------------- Phase C3: loss ----------------
  // rowloss = 3*lse(5*sim[t, j!=t]) - sum_pos 5*sim[t,p]; |z|<=5 -> no max pass.
  {
    const int t = tid >> 1;
    const int h = tid & 1;
    float s = 0.f, psum = 0.f;
    const int c0 = h * 64;
    #pragma unroll 8
    for (int jj = 0; jj < 64; ++jj) {
      const int j = c0 + jj;
      const float z = 5.0f * bf2f(SM[t * GSTRIDE + j]);
      const bool valid = (j != t);
      s += valid ? __expf(z) : 0.f;
      psum += (valid && (((j ^ t) & 31) == 0)) ? z : 0.f;
    }
    s += __shfl_xor(s, 1, 64);
    psum += __shfl_xor(psum, 1, 64);
    float rowloss = (h == 0) ? (3.0f * __logf(s) - psum) : 0.f;
    #pragma unroll
    for (int off = 32; off >= 1; off >>= 1) rowloss += __shfl_xor(rowloss, off, 64);
    if ((tid & 63) == 0) red[tid >> 6] = rowloss;
    __syncthreads();
    if (tid == 0) {
      const float blocksum = red[0] + red[1] + red[2] + red[3];
      atomicAdd(out, blocksum * (1.0f / ((float)TT * (float)NB)));
    }
  }
}

extern "C" void kernel_launch(void* const* d_in, const int* in_sizes, int n_in,
                              void* d_out, int out_size, void* d_ws, size_t ws_size,
                              hipStream_t stream) {
  const float* emb = (const float*)d_in[0];
  float* out = (float*)d_out;
  hipMemsetAsync(d_out, 0, sizeof(float), stream);  // out[0] accumulated via atomicAdd
  contrastive_kernel<<<dim3(NB), dim3(256), 0, stream>>>(emb, out);
}